// Round 1
// baseline (287.625 us; speedup 1.0000x reference)
//
#include <hip/hip_runtime.h>
#include <hip/hip_bf16.h>

// SimilarityPreserving loss, restructured:
//   loss = (1/b^2) * sum_i [ A/sa^2 + B/sb^2 - 2C/(sa*sb) ]
//   A_i = sum_j ct(i,j)^2, B_i = sum_j cs(i,j)^2, C_i = sum_j ct*cs
//   ct/cs = cosine grams = GEMMs over row-normalized inputs (bf16 MFMA).
// Temperature cancels in row-normalization (eps never binds); COS_EPS never
// binds for random-normal 128-dim rows (norm ~ 11). Verified error budget:
// bf16 input rounding -> ~3e-5 random per-row rho error -> ~1e-8 on loss.

typedef __attribute__((ext_vector_type(8))) short short8;   // 8 bf16 = 4 VGPRs
typedef __attribute__((ext_vector_type(4))) float float4v;  // MFMA C/D

#define BSZ 8192
#define DIM 128

// ---------------------------------------------------------------- normalize
// One wave per row: fp32 norm, write bf16 row-normalized vector.
__global__ __launch_bounds__(256) void normalize_all(
    const float* __restrict__ x0, const float* __restrict__ x1,
    const float* __restrict__ x2, const float* __restrict__ x3,
    __hip_bfloat16* __restrict__ out)
{
    int gw   = (blockIdx.x * 256 + threadIdx.x) >> 6;  // global wave = row id
    int lane = threadIdx.x & 63;
    int mat  = gw >> 13;           // 0..3
    int row  = gw & (BSZ - 1);
    const float* in = (mat == 0) ? x0 : (mat == 1) ? x1 : (mat == 2) ? x2 : x3;

    const float2* rp = (const float2*)(in + (size_t)row * DIM);
    float2 v = rp[lane];
    float ss = v.x * v.x + v.y * v.y;
    #pragma unroll
    for (int off = 1; off < 64; off <<= 1) ss += __shfl_xor(ss, off);
    float nrm = sqrtf(ss);
    float inv = nrm > 0.f ? 1.f / nrm : 0.f;   // cosine denom max(nx*ny,eps) never binds

    __hip_bfloat162* op = (__hip_bfloat162*)(out + ((size_t)mat * BSZ + row) * DIM);
    __hip_bfloat162 o;
    o.x = __float2bfloat16(v.x * inv);
    o.y = __float2bfloat16(v.y * inv);
    op[lane] = o;
}

// ---------------------------------------------------------------- dual gram
// 128x128 output tile per block (256 thr = 4 waves in 2x2), K = 128 in one
// staging pass. Two passes over the SAME tile coords: (Xs,Ys) then (Xt,Yt).
// LDS tiles are XOR-swizzled at 16B-chunk granularity: chunk c of row r is
// stored at chunk (c ^ (r&7)) -> uniform bank-group use for both the
// ds_write_b128 staging and the ds_read_b128 fragment loads.
__global__ __launch_bounds__(256, 2) void gram_kernel(
    const __hip_bfloat16* __restrict__ Xs, const __hip_bfloat16* __restrict__ Ys,
    const __hip_bfloat16* __restrict__ Xt, const __hip_bfloat16* __restrict__ Yt,
    float* __restrict__ accA, float* __restrict__ accB, float* __restrict__ accC)
{
    __shared__ __hip_bfloat16 lX[128 * DIM];  // 32 KB
    __shared__ __hip_bfloat16 lY[128 * DIM];  // 32 KB

    const int tid  = threadIdx.x;
    const int lane = tid & 63;
    const int wave = tid >> 6;
    const int wr = wave & 1;   // wave row within 2x2
    const int wc = wave >> 1;  // wave col
    const int bi = blockIdx.y; // row tile
    const int bj = blockIdx.x; // col tile
    const int q  = lane >> 4;  // quad id 0..3
    const int l15 = lane & 15;

    short8* lx = (short8*)lX;
    short8* ly = (short8*)lY;

    float4v acc_s[4][4];
    float4v acc_t[4][4];
    #pragma unroll
    for (int i = 0; i < 4; ++i)
        #pragma unroll
        for (int j = 0; j < 4; ++j) {
            acc_s[i][j] = (float4v){0.f, 0.f, 0.f, 0.f};
            acc_t[i][j] = (float4v){0.f, 0.f, 0.f, 0.f};
        }

    #pragma unroll
    for (int pass = 0; pass < 2; ++pass) {
        const __hip_bfloat16* gx = pass ? Xt : Xs;
        const __hip_bfloat16* gy = pass ? Yt : Ys;
        const short8* gsx = (const short8*)(gx + (size_t)bi * 128 * DIM);
        const short8* gsy = (const short8*)(gy + (size_t)bj * 128 * DIM);

        if (pass) __syncthreads();  // protect lX/lY while pass-0 MFMA reads finish
        // stage 32KB + 32KB: 2048 chunks of 16B each, 8 iters x 256 thr
        #pragma unroll
        for (int it = 0; it < 8; ++it) {
            int c   = it * 256 + tid;       // global chunk id: row = c>>4, col-chunk = c&15
            int row = c >> 4;
            int col = c & 15;
            int sw  = row * 16 + (col ^ (row & 7));
            short8 vx = gsx[c];
            short8 vy = gsy[c];
            lx[sw] = vx;
            ly[sw] = vy;
        }
        __syncthreads();

        // K = 128 = 4 MFMA steps of 32; chunk index for step kk is kk*4 + q
        #pragma unroll
        for (int kk = 0; kk < 4; ++kk) {
            short8 a[4], b[4];
            #pragma unroll
            for (int f = 0; f < 4; ++f) {
                int ar = wr * 64 + f * 16 + l15;
                int ac = kk * 4 + q;
                a[f] = lx[ar * 16 + (ac ^ (ar & 7))];
                int br = wc * 64 + f * 16 + l15;
                b[f] = ly[br * 16 + (ac ^ (br & 7))];
            }
            #pragma unroll
            for (int fi = 0; fi < 4; ++fi)
                #pragma unroll
                for (int fj = 0; fj < 4; ++fj) {
                    if (pass == 0)
                        acc_s[fi][fj] = __builtin_amdgcn_mfma_f32_16x16x32_bf16(
                            a[fi], b[fj], acc_s[fi][fj], 0, 0, 0);
                    else
                        acc_t[fi][fj] = __builtin_amdgcn_mfma_f32_16x16x32_bf16(
                            a[fi], b[fj], acc_t[fi][fj], 0, 0, 0);
                }
        }
    }

    // Per-row reduction. D layout: row = q*4 + r (+fi*16), col = l15 (+fj*16).
    // Sum over cols = sum over fj then over the 16 lanes of the same quad.
    #pragma unroll
    for (int fi = 0; fi < 4; ++fi) {
        #pragma unroll
        for (int r = 0; r < 4; ++r) {
            float pa = 0.f, pb = 0.f, pc = 0.f;
            #pragma unroll
            for (int fj = 0; fj < 4; ++fj) {
                float s = acc_s[fi][fj][r];
                float t = acc_t[fi][fj][r];
                pa += t * t;
                pb += s * s;
                pc += t * s;
            }
            #pragma unroll
            for (int off = 1; off < 16; off <<= 1) {
                pa += __shfl_xor(pa, off);
                pb += __shfl_xor(pb, off);
                pc += __shfl_xor(pc, off);
            }
            if (l15 == 0) {
                int row = bi * 128 + wr * 64 + fi * 16 + q * 4 + r;
                atomicAdd(&accA[row], pa);
                atomicAdd(&accB[row], pb);
                atomicAdd(&accC[row], pc);
            }
        }
    }
}

// ---------------------------------------------------------------- finalize
__global__ __launch_bounds__(256) void finalize_kernel(
    const float* __restrict__ A, const float* __restrict__ B,
    const float* __restrict__ C, float* __restrict__ out)
{
    __shared__ float red[4];
    float acc = 0.f;
    for (int i = threadIdx.x; i < BSZ; i += 256) {
        float a = A[i], b = B[i], c = C[i];
        float sa = fmaxf(sqrtf(a), 1e-12f);  // NORM_EPS
        float sb = fmaxf(sqrtf(b), 1e-12f);
        acc += a / (sa * sa) + b / (sb * sb) - 2.f * c / (sa * sb);
    }
    #pragma unroll
    for (int off = 1; off < 64; off <<= 1) acc += __shfl_xor(acc, off);
    int wv = threadIdx.x >> 6, lane = threadIdx.x & 63;
    if (lane == 0) red[wv] = acc;
    __syncthreads();
    if (threadIdx.x == 0)
        out[0] = (red[0] + red[1] + red[2] + red[3]) / ((float)BSZ * (float)BSZ);
}

// ---------------------------------------------------------------- launch
extern "C" void kernel_launch(void* const* d_in, const int* in_sizes, int n_in,
                              void* d_out, int out_size, void* d_ws, size_t ws_size,
                              hipStream_t stream) {
    const float* zxs = (const float*)d_in[0];
    const float* zys = (const float*)d_in[1];
    const float* zxt = (const float*)d_in[2];
    const float* zyt = (const float*)d_in[3];
    // d_in[4] = temperature: cancels exactly in row-normalization, unused.
    float* out = (float*)d_out;

    char* ws = (char*)d_ws;
    __hip_bfloat16* nrm = (__hip_bfloat16*)ws;  // 4 matrices, 2 MB each = 8 MB
    __hip_bfloat16* nXs = nrm;
    __hip_bfloat16* nYs = nXs + (size_t)BSZ * DIM;
    __hip_bfloat16* nXt = nYs + (size_t)BSZ * DIM;
    __hip_bfloat16* nYt = nXt + (size_t)BSZ * DIM;
    float* accA = (float*)(ws + 4 * (size_t)BSZ * DIM * sizeof(__hip_bfloat16));
    float* accB = accA + BSZ;
    float* accC = accB + BSZ;

    hipMemsetAsync(accA, 0, 3 * BSZ * sizeof(float), stream);

    // 4*8192 rows, one wave each, 4 waves per block
    normalize_all<<<(4 * BSZ) / 4, 256, 0, stream>>>(zxs, zys, zxt, zyt, nrm);

    dim3 grid(BSZ / 128, BSZ / 128);  // 64 x 64 tiles
    gram_kernel<<<grid, 256, 0, stream>>>(nXs, nYs, nXt, nYt, accA, accB, accC);

    finalize_kernel<<<1, 256, 0, stream>>>(accA, accB, accC, out);
}

// Round 2
// 129.237 us; speedup vs baseline: 2.2256x; 2.2256x over previous
//
#include <hip/hip_runtime.h>
#include <hip/hip_bf16.h>

// SimilarityPreserving loss via row-sums only:
//   loss = (1/b^2) * sum_i [ A/sa^2 + B/sb^2 - 2C/(sa*sb) ]
//   A_i = sum_j ct(i,j)^2, B_i = sum_j cs(i,j)^2, C_i = sum_j ct*cs
// ct/cs are cosine grams over row-normalized inputs (bf16 MFMA, fp32 acc).
// Temperature cancels in row-normalization; eps terms never bind (row norms
// ~11). The sim matrices are never materialized.
//
// gram_kernel structure (m97-style): block = 128-row strip x 1024-col group.
// A fragments (s+t) in registers (64 VGPR/wave, loaded once). Loop over 8
// column tiles: stage Ys+Yt tile (64 KB) via global_load_lds width-16 with
// global-side XOR chunk swizzle (so ds_read_b128 frag reads are 2-way max
// bank aliasing = free), 2-barrier loop, 512 MFMA per tile per block.
// Row-sum partials folded in-register; one 16-lane shuffle + atomicAdd at end.

typedef __attribute__((ext_vector_type(8))) short short8;   // 8 bf16 = 4 VGPRs
typedef __attribute__((ext_vector_type(4))) float float4v;  // MFMA C/D

#define BSZ 8192
#define DIM 128

__device__ __forceinline__ void async_ld16(void* lds, const void* g) {
    __builtin_amdgcn_global_load_lds(
        (const __attribute__((address_space(1))) void*)g,
        (__attribute__((address_space(3))) void*)lds, 16, 0, 0);
}

// ---------------------------------------------------------------- normalize
// One wave per row: fp32 norm, write bf16 row-normalized vector.
__global__ __launch_bounds__(256) void normalize_all(
    const float* __restrict__ x0, const float* __restrict__ x1,
    const float* __restrict__ x2, const float* __restrict__ x3,
    __hip_bfloat16* __restrict__ out)
{
    int gw   = (blockIdx.x * 256 + threadIdx.x) >> 6;  // global wave = row id
    int lane = threadIdx.x & 63;
    int mat  = gw >> 13;           // 0..3
    int row  = gw & (BSZ - 1);
    const float* in = (mat == 0) ? x0 : (mat == 1) ? x1 : (mat == 2) ? x2 : x3;

    const float2* rp = (const float2*)(in + (size_t)row * DIM);
    float2 v = rp[lane];
    float ss = v.x * v.x + v.y * v.y;
    #pragma unroll
    for (int off = 1; off < 64; off <<= 1) ss += __shfl_xor(ss, off);
    float nrm = sqrtf(ss);
    float inv = nrm > 0.f ? 1.f / nrm : 0.f;

    __hip_bfloat162* op = (__hip_bfloat162*)(out + ((size_t)mat * BSZ + row) * DIM);
    __hip_bfloat162 o;
    o.x = __float2bfloat16(v.x * inv);
    o.y = __float2bfloat16(v.y * inv);
    op[lane] = o;
}

// ---------------------------------------------------------------- dual gram
__global__ __launch_bounds__(256, 2) void gram_kernel(
    const __hip_bfloat16* __restrict__ Xs, const __hip_bfloat16* __restrict__ Ys,
    const __hip_bfloat16* __restrict__ Xt, const __hip_bfloat16* __restrict__ Yt,
    float* __restrict__ accA, float* __restrict__ accB, float* __restrict__ accC)
{
    __shared__ __hip_bfloat16 lBs[128 * DIM];  // 32 KB: Ys col tile
    __shared__ __hip_bfloat16 lBt[128 * DIM];  // 32 KB: Yt col tile

    const int tid  = threadIdx.x;
    const int lane = tid & 63;
    const int wave = tid >> 6;
    const int q    = lane >> 4;   // quad 0..3
    const int l15  = lane & 15;
    const int strip = blockIdx.y; // 0..63 : rows strip*128 .. +127
    const int grp   = blockIdx.x; // 0..7  : cols grp*1024 .. +1023

    // ---- A fragments in registers: wave owns rows strip*128 + wave*32 .. +31
    // MFMA A layout: lane holds A[m=l15][k = q*8 + j]; for kfrag kk the 8
    // elements are X[row][kk*32 + q*8 .. +8] = short8 chunk (row*16 + kk*4+q).
    short8 as[2][4], at[2][4];
    {
        const int rbase = strip * 128 + wave * 32;
        #pragma unroll
        for (int rb = 0; rb < 2; ++rb) {
            int row = rbase + rb * 16 + l15;
            const short8* xs = (const short8*)(Xs + (size_t)row * DIM);
            const short8* xt = (const short8*)(Xt + (size_t)row * DIM);
            #pragma unroll
            for (int kk = 0; kk < 4; ++kk) {
                as[rb][kk] = xs[kk * 4 + q];
                at[rb][kk] = xt[kk * 4 + q];
            }
        }
    }

    float4v pa0 = {0.f,0.f,0.f,0.f}, pb0 = pa0, pc0 = pa0;
    float4v pa1 = pa0, pb1 = pa0, pc1 = pa0;

    short8* ls = (short8*)lBs;
    short8* lt = (short8*)lBt;

    for (int j = 0; j < 8; ++j) {
        const int ct = grp * 8 + j;  // column tile id 0..63
        const short8* gs = (const short8*)(Ys + (size_t)ct * 128 * DIM);
        const short8* gt = (const short8*)(Yt + (size_t)ct * 128 * DIM);

        if (j) __syncthreads();  // previous tile's readers done
        // Stage 2 x 32 KB. LDS chunk s holds global chunk row*16 + (sc^(row&7))
        // (swizzle applied on the GLOBAL side; LDS side must stay linear for
        // global_load_lds's wave-uniform-base + lane*16 addressing).
        #pragma unroll
        for (int it = 0; it < 8; ++it) {
            int s   = it * 256 + tid;    // 0..2047
            int row = s >> 4, sc = s & 15;
            int g   = (row << 4) + (sc ^ (row & 7));
            async_ld16(&ls[s], &gs[g]);
            async_ld16(&lt[s], &gt[g]);
        }
        __syncthreads();  // vmcnt(0) drain: DMA complete

        // 8 column blocks of 16; per cb: 8 ds_read_b128 + 16 MFMA + 24 VALU
        #pragma unroll
        for (int cb = 0; cb < 8; ++cb) {
            short8 bs[4], bt[4];
            #pragma unroll
            for (int kk = 0; kk < 4; ++kk) {
                // B layout: lane holds B[k=q*8+j][n=l15] = Ycol[cb*16+l15][k];
                // stored swizzled: chunk = row*16 + (kc ^ (row&7)), row&7==l15&7
                int chunk = ((cb * 16 + l15) << 4) + ((kk * 4 + q) ^ (l15 & 7));
                bs[kk] = ls[chunk];
                bt[kk] = lt[chunk];
            }
            float4v ds0 = {0.f,0.f,0.f,0.f}, ds1 = ds0, dt0 = ds0, dt1 = ds0;
            #pragma unroll
            for (int kk = 0; kk < 4; ++kk) {
                ds0 = __builtin_amdgcn_mfma_f32_16x16x32_bf16(as[0][kk], bs[kk], ds0, 0, 0, 0);
                ds1 = __builtin_amdgcn_mfma_f32_16x16x32_bf16(as[1][kk], bs[kk], ds1, 0, 0, 0);
                dt0 = __builtin_amdgcn_mfma_f32_16x16x32_bf16(at[0][kk], bt[kk], dt0, 0, 0, 0);
                dt1 = __builtin_amdgcn_mfma_f32_16x16x32_bf16(at[1][kk], bt[kk], dt1, 0, 0, 0);
            }
            #pragma unroll
            for (int r = 0; r < 4; ++r) {
                pa0[r] += dt0[r] * dt0[r];
                pb0[r] += ds0[r] * ds0[r];
                pc0[r] += dt0[r] * ds0[r];
                pa1[r] += dt1[r] * dt1[r];
                pb1[r] += ds1[r] * ds1[r];
                pc1[r] += dt1[r] * ds1[r];
            }
        }
    }

    // ---- epilogue: D row = q*4 + r, col = l15. Sum over cols = reduce over
    // the 16 lanes of each quad-group (lanes q*16..q*16+15, shfl_xor 1,2,4,8).
    #pragma unroll
    for (int rb = 0; rb < 2; ++rb) {
        float4v a = rb ? pa1 : pa0, b = rb ? pb1 : pb0, c = rb ? pc1 : pc0;
        #pragma unroll
        for (int r = 0; r < 4; ++r) {
            float va = a[r], vb = b[r], vc = c[r];
            #pragma unroll
            for (int off = 1; off < 16; off <<= 1) {
                va += __shfl_xor(va, off);
                vb += __shfl_xor(vb, off);
                vc += __shfl_xor(vc, off);
            }
            if (l15 == 0) {
                int row = strip * 128 + wave * 32 + rb * 16 + q * 4 + r;
                atomicAdd(&accA[row], va);
                atomicAdd(&accB[row], vb);
                atomicAdd(&accC[row], vc);
            }
        }
    }
}

// ---------------------------------------------------------------- finalize
__global__ __launch_bounds__(256) void finalize_kernel(
    const float* __restrict__ A, const float* __restrict__ B,
    const float* __restrict__ C, float* __restrict__ out)
{
    __shared__ float red[4];
    float acc = 0.f;
    for (int i = threadIdx.x; i < BSZ; i += 256) {
        float a = A[i], b = B[i], c = C[i];
        float sa = fmaxf(sqrtf(a), 1e-12f);  // NORM_EPS
        float sb = fmaxf(sqrtf(b), 1e-12f);
        acc += a / (sa * sa) + b / (sb * sb) - 2.f * c / (sa * sb);
    }
    #pragma unroll
    for (int off = 1; off < 64; off <<= 1) acc += __shfl_xor(acc, off);
    int wv = threadIdx.x >> 6, lane = threadIdx.x & 63;
    if (lane == 0) red[wv] = acc;
    __syncthreads();
    if (threadIdx.x == 0)
        out[0] = (red[0] + red[1] + red[2] + red[3]) / ((float)BSZ * (float)BSZ);
}

// ---------------------------------------------------------------- launch
extern "C" void kernel_launch(void* const* d_in, const int* in_sizes, int n_in,
                              void* d_out, int out_size, void* d_ws, size_t ws_size,
                              hipStream_t stream) {
    const float* zxs = (const float*)d_in[0];
    const float* zys = (const float*)d_in[1];
    const float* zxt = (const float*)d_in[2];
    const float* zyt = (const float*)d_in[3];
    // d_in[4] = temperature: cancels exactly in row-normalization, unused.
    float* out = (float*)d_out;

    char* ws = (char*)d_ws;
    __hip_bfloat16* nrm = (__hip_bfloat16*)ws;  // 4 matrices, 2 MB each = 8 MB
    __hip_bfloat16* nXs = nrm;
    __hip_bfloat16* nYs = nXs + (size_t)BSZ * DIM;
    __hip_bfloat16* nXt = nYs + (size_t)BSZ * DIM;
    __hip_bfloat16* nYt = nXt + (size_t)BSZ * DIM;
    float* accA = (float*)(ws + 4 * (size_t)BSZ * DIM * sizeof(__hip_bfloat16));
    float* accB = accA + BSZ;
    float* accC = accB + BSZ;

    hipMemsetAsync(accA, 0, 3 * BSZ * sizeof(float), stream);

    normalize_all<<<(4 * BSZ) / 4, 256, 0, stream>>>(zxs, zys, zxt, zyt, nrm);

    dim3 grid(8, 64);  // 8 col groups x 64 row strips = 512 blocks = 2/CU
    gram_kernel<<<grid, 256, 0, stream>>>(nXs, nYs, nXt, nYt, accA, accB, accC);

    finalize_kernel<<<1, 256, 0, stream>>>(accA, accB, accC, out);
}